// Round 1
// baseline (268.012 us; speedup 1.0000x reference)
//
#include <hip/hip_runtime.h>
#include <hip/hip_bf16.h>

typedef __attribute__((ext_vector_type(4))) float f32x4;
typedef __attribute__((ext_vector_type(8))) short short8;
typedef unsigned short u16;

#define MFMA(a, b, c) __builtin_amdgcn_mfma_f32_16x16x32_bf16((a), (b), (c), 0, 0, 0)

static constexpr int EMBED = 768;
static constexpr int NH = 12;
static constexpr int HD = 64;
static constexpr int BATCH = 8;
static constexpr int SEQ = 1024;

__device__ __forceinline__ u16 f2bu(float f) {
    __hip_bfloat16 h = __float2bfloat16(f);
    u16 u; __builtin_memcpy(&u, &h, 2); return u;
}
__device__ __forceinline__ float bu2f(u16 u) {
    __hip_bfloat16 h; __builtin_memcpy(&h, &u, 2); return __bfloat162float(h);
}

// ---------------- fp32 -> bf16 convert (vectorized) ----------------
__global__ void cvt_bf16_k(const float* __restrict__ in, u16* __restrict__ out, int n) {
    int i = (blockIdx.x * blockDim.x + threadIdx.x) * 4;
    if (i >= n) return;
    float4 v = *reinterpret_cast<const float4*>(in + i);
    ushort4 o;
    o.x = f2bu(v.x); o.y = f2bu(v.y); o.z = f2bu(v.z); o.w = f2bu(v.w);
    *reinterpret_cast<ushort4*>(out + i) = o;
}

// ---------------- bf16 B^T GEMM: C[M,N] = A[M,K] * Bw[N,K]^T + bias ----------------
// 128x128 tile, BK=64, 4 waves (2x2), each wave 64x64 via 4x4 fragments of 16x16x32.
// LDS staged via global_load_lds(16B) with XOR swizzle (pre-swizzled source + swizzled read).
// EPI 0: scatter to Q (x0.125), K, Vt (bf16).  EPI 1: fp32 out.
template <int EPI>
__global__ __launch_bounds__(256)
void gemm_bt_k(const u16* __restrict__ A, const u16* __restrict__ Bw,
               const float* __restrict__ bias,
               u16* __restrict__ q_out, u16* __restrict__ k_out,
               u16* __restrict__ vt_out, float* __restrict__ f_out)
{
    __shared__ __attribute__((aligned(16))) char smem[32768];
    char* As = smem;
    char* Bs = smem + 16384;
    const int tid  = threadIdx.x;
    const int wave = tid >> 6, lane = tid & 63;
    const int hi   = lane >> 4, l15 = lane & 15;
    const int wr   = wave >> 1, wc = wave & 1;
    const int bm   = blockIdx.x, bn = blockIdx.y;

    f32x4 acc[4][4] = {};

    const size_t arow0 = (size_t)bm * 128;
    const size_t brow0 = (size_t)bn * 128;

    for (int kt = 0; kt < EMBED; kt += 64) {
        __syncthreads();   // previous tile's reads complete
#pragma unroll
        for (int c = 0; c < 4; ++c) {
            int ck   = c * 4 + wave;          // 16 chunks of 1KB
            int p    = ck * 1024 + lane * 16; // byte position in 16KB tile
            int row  = p >> 7;                // tile row (128B rows)
            int pcol = (p & 127) ^ ((row & 7) << 4); // inverse-swizzled source col (bytes)
            const u16* srcA = A  + (arow0 + row) * EMBED + kt + (pcol >> 1);
            const u16* srcB = Bw + (brow0 + row) * EMBED + kt + (pcol >> 1);
            __builtin_amdgcn_global_load_lds((const __attribute__((address_space(1))) void*)srcA,
                                             (__attribute__((address_space(3))) void*)(As + ck * 1024), 16, 0, 0);
            __builtin_amdgcn_global_load_lds((const __attribute__((address_space(1))) void*)srcB,
                                             (__attribute__((address_space(3))) void*)(Bs + ck * 1024), 16, 0, 0);
        }
        __syncthreads();   // staging visible
#pragma unroll
        for (int kk = 0; kk < 2; ++kk) {
            short8 af[4], bf[4];
#pragma unroll
            for (int mi = 0; mi < 4; ++mi) {
                int R  = wr * 64 + mi * 16 + l15;
                int Cb = kk * 64 + hi * 16;
                af[mi] = *reinterpret_cast<const short8*>(As + R * 128 + (Cb ^ ((R & 7) << 4)));
            }
#pragma unroll
            for (int ni = 0; ni < 4; ++ni) {
                int R  = wc * 64 + ni * 16 + l15;
                int Cb = kk * 64 + hi * 16;
                bf[ni] = *reinterpret_cast<const short8*>(Bs + R * 128 + (Cb ^ ((R & 7) << 4)));
            }
#pragma unroll
            for (int mi = 0; mi < 4; ++mi)
#pragma unroll
                for (int ni = 0; ni < 4; ++ni)
                    acc[mi][ni] = MFMA(af[mi], bf[ni], acc[mi][ni]);
        }
    }

    // epilogue: C/D layout col = lane&15, row = 4*(lane>>4)+reg
#pragma unroll
    for (int mi = 0; mi < 4; ++mi) {
        int crow0 = bm * 128 + wr * 64 + mi * 16 + hi * 4;
#pragma unroll
        for (int ni = 0; ni < 4; ++ni) {
            int ccol = bn * 128 + wc * 64 + ni * 16 + l15;
            float bv = bias[ccol];
#pragma unroll
            for (int r = 0; r < 4; ++r) {
                float v  = acc[mi][ni][r] + bv;
                int crow = crow0 + r;
                if constexpr (EPI == 0) {
                    int which = ccol / 768;
                    int rem   = ccol - which * 768;
                    int hh = rem >> 6, hd = rem & 63;
                    int bb = crow >> 10, nn = crow & 1023;
                    size_t bh = (size_t)(bb * NH + hh);
                    if (which == 0)      q_out[(bh * SEQ + nn) * HD + hd] = f2bu(v * 0.125f); // fold SCALE
                    else if (which == 1) k_out[(bh * SEQ + nn) * HD + hd] = f2bu(v);
                    else                 vt_out[(bh * HD + hd) * SEQ + nn] = f2bu(v);        // V transposed
                } else {
                    f_out[(size_t)crow * EMBED + ccol] = v;
                }
            }
        }
    }
}

// ---------------- flash attention: 1 workgroup = (b,h) x 64 q-rows, 4 waves x 16 rows ----------------
__global__ __launch_bounds__(256)
void attn_k(const u16* __restrict__ Q, const u16* __restrict__ K,
            const u16* __restrict__ Vt, u16* __restrict__ AO)
{
    __shared__ __attribute__((aligned(16))) u16 plds[4][16][72]; // stride 144B: <=2-way conflicts
    const int tid = threadIdx.x;
    const int w   = tid >> 6, lane = tid & 63;
    const int hi  = lane >> 4, l15 = lane & 15;
    const int bh  = blockIdx.y;
    const int q0  = blockIdx.x * 64 + w * 16;
    const u16* Qh = Q  + (size_t)bh * SEQ * HD;
    const u16* Kh = K  + (size_t)bh * SEQ * HD;
    const u16* Vh = Vt + (size_t)bh * HD * SEQ;

    short8 qf[2];
#pragma unroll
    for (int dh = 0; dh < 2; ++dh)
        qf[dh] = *reinterpret_cast<const short8*>(Qh + (size_t)(q0 + l15) * HD + dh * 32 + hi * 8);

    f32x4 accO[4] = {};
    float m[4], l[4];
#pragma unroll
    for (int r = 0; r < 4; ++r) { m[r] = -1e30f; l[r] = 0.f; }

    for (int kt = 0; kt < SEQ; kt += 64) {
        // S tile: 16q x 64k, Q pre-scaled by 0.125
        f32x4 s[4] = {};
#pragma unroll
        for (int kb = 0; kb < 4; ++kb)
#pragma unroll
            for (int dh = 0; dh < 2; ++dh) {
                short8 kf = *reinterpret_cast<const short8*>(
                    Kh + (size_t)(kt + kb * 16 + l15) * HD + dh * 32 + hi * 8);
                s[kb] = MFMA(qf[dh], kf, s[kb]);
            }
        // online softmax; lane holds S[q=4*hi+r][k=kb*16+l15]
#pragma unroll
        for (int r = 0; r < 4; ++r) {
            float tm = fmaxf(fmaxf(s[0][r], s[1][r]), fmaxf(s[2][r], s[3][r]));
#pragma unroll
            for (int off = 1; off < 16; off <<= 1)
                tm = fmaxf(tm, __shfl_xor(tm, off, 64));
            float mn = fmaxf(m[r], tm);
            float sc = __expf(m[r] - mn);
            float ps = 0.f;
#pragma unroll
            for (int kb = 0; kb < 4; ++kb) {
                float p = __expf(s[kb][r] - mn);
                u16 pb  = f2bu(p);
                plds[w][4 * hi + r][kb * 16 + l15] = pb;
                ps += bu2f(pb); // sum the rounded P so l matches PV exactly
            }
#pragma unroll
            for (int off = 1; off < 16; off <<= 1)
                ps += __shfl_xor(ps, off, 64);
            l[r] = l[r] * sc + ps;
            m[r] = mn;
#pragma unroll
            for (int db = 0; db < 4; ++db) accO[db][r] *= sc;
        }
        // read P back in A-operand layout (per-wave region; in-order DS pipe, no barrier)
        short8 pa[2];
#pragma unroll
        for (int kk = 0; kk < 2; ++kk)
            pa[kk] = *reinterpret_cast<const short8*>(&plds[w][l15][kk * 32 + hi * 8]);
        __builtin_amdgcn_sched_barrier(0); // keep next tile's P writes below these reads
        // O += P * V  (B-operand read from transposed V: contiguous b128)
#pragma unroll
        for (int db = 0; db < 4; ++db)
#pragma unroll
            for (int kk = 0; kk < 2; ++kk) {
                short8 vf = *reinterpret_cast<const short8*>(
                    Vh + (size_t)(db * 16 + l15) * SEQ + kt + kk * 32 + hi * 8);
                accO[db] = MFMA(pa[kk], vf, accO[db]);
            }
    }
    const int bb = bh / NH, hh = bh - bb * NH;
#pragma unroll
    for (int r = 0; r < 4; ++r) {
        float inv  = 1.f / l[r];
        size_t row = (size_t)bb * SEQ + q0 + 4 * hi + r;
#pragma unroll
        for (int db = 0; db < 4; ++db)
            AO[row * EMBED + hh * HD + db * 16 + l15] = f2bu(accO[db][r] * inv);
    }
}

// ---------------- launch ----------------
extern "C" void kernel_launch(void* const* d_in, const int* in_sizes, int n_in,
                              void* d_out, int out_size, void* d_ws, size_t ws_size,
                              hipStream_t stream)
{
    const float* x      = (const float*)d_in[0];
    const float* qkv_w  = (const float*)d_in[1];
    const float* qkv_b  = (const float*)d_in[2];
    const float* proj_w = (const float*)d_in[3];
    const float* proj_b = (const float*)d_in[4];
    float* out = (float*)d_out;

    char* ws = (char*)d_ws;
    u16* xb  = (u16*)(ws);                 // 8192x768 bf16   = 12,582,912 B
    u16* wb  = (u16*)(ws + 12582912);      // 2304x768 bf16   =  3,538,944 B
    u16* pw  = (u16*)(ws + 16121856);      //  768x768 bf16   =  1,179,648 B
    u16* qb  = (u16*)(ws + 17301504);      // [b,h,n,hd] bf16 = 12,582,912 B
    u16* kb  = (u16*)(ws + 29884416);      // [b,h,n,hd] bf16
    u16* vt  = (u16*)(ws + 42467328);      // [b,h,hd,n] bf16
    u16* ao  = (u16*)(ws + 55050240);      // 8192x768 bf16
    // total ws use: 67,633,152 B

    cvt_bf16_k<<<6144, 256, 0, stream>>>(x,      xb, BATCH * SEQ * EMBED);
    cvt_bf16_k<<<1728, 256, 0, stream>>>(qkv_w,  wb, 3 * EMBED * EMBED);
    cvt_bf16_k<<<576,  256, 0, stream>>>(proj_w, pw, EMBED * EMBED);

    gemm_bt_k<0><<<dim3(64, 18), 256, 0, stream>>>(xb, wb, qkv_b, qb, kb, vt, nullptr);
    attn_k<<<dim3(16, 96), 256, 0, stream>>>(qb, kb, vt, ao);
    gemm_bt_k<1><<<dim3(64, 6), 256, 0, stream>>>(ao, pw, proj_b, nullptr, nullptr, nullptr, out);
}